// Round 16
// baseline (129.335 us; speedup 1.0000x reference)
//
#include <hip/hip_runtime.h>

typedef __attribute__((ext_vector_type(8))) short short8v;
typedef __attribute__((ext_vector_type(4))) float f32x4;
typedef __attribute__((ext_vector_type(2))) unsigned int uint2v;

#define NN 8192
#define HDIM 64
#define KDIM 128
#define LOG2E 1.44269504088896340736f

#define PIN() asm volatile("" ::: "memory")
// Barrier WITHOUT vmcnt drain: LDS hazards need only lgkmcnt(0).
#define BAR() asm volatile("s_waitcnt lgkmcnt(0)\n\ts_barrier" ::: "memory")

__device__ __forceinline__ unsigned short f2b(float f) {
    unsigned int u = __float_as_uint(f);
    return (unsigned short)((u + 0x7fffu + ((u >> 16) & 1u)) >> 16);
}

// ---------------- Kernel 1 (R14/R15-verified): H = X@W, consts, HbT bf16, zero-fill ----
__global__ __launch_bounds__(256) void gat_prep(
    const float* __restrict__ X, const float* __restrict__ W,
    const float* __restrict__ al, const float* __restrict__ ar,
    unsigned short* __restrict__ HbT, float* __restrict__ el2p,
    float* __restrict__ cpv, float* __restrict__ erp,
    float* __restrict__ outz, float* __restrict__ dsumz)
{
    __shared__ float Wl[KDIM * HDIM];
    const int t = threadIdx.x;
    {   // zero-fill accumulation buffers (131072 float4 = 2MB out; 8192 dsum)
        const int gt = blockIdx.x * 256 + t;
        const float4 z = {0.f, 0.f, 0.f, 0.f};
        float4* ov = (float4*)outz;
        ov[gt] = z;
        ov[gt + 65536] = z;
        if (blockIdx.x < 32) dsumz[gt] = 0.f;
    }
    {
        const float4* Wv = (const float4*)W;
        float4* Wlv = (float4*)Wl;
#pragma unroll
        for (int s = 0; s < 8; ++s) Wlv[t + s * 256] = Wv[t + s * 256];
    }
    __syncthreads();
    const int row = blockIdx.x * 32 + (t >> 3);
    const int cg = t & 7;
    const int c0 = cg * 8;
    float al8[8], ar8[8];
#pragma unroll
    for (int j = 0; j < 8; ++j) { al8[j] = al[c0 + j]; ar8[j] = ar[c0 + j]; }
    float acc[8];
#pragma unroll
    for (int j = 0; j < 8; ++j) acc[j] = 0.f;
    const float4* Xv = (const float4*)(X + row * KDIM);
    for (int k4 = 0; k4 < 32; ++k4) {
        float4 x4 = Xv[k4];
        float xs[4] = {x4.x, x4.y, x4.z, x4.w};
#pragma unroll
        for (int kk = 0; kk < 4; ++kk) {
            const int k = k4 * 4 + kk;
            const float x = xs[kk];
            const float4 w0 = *(const float4*)&Wl[k * HDIM + c0];
            const float4 w1 = *(const float4*)&Wl[k * HDIM + c0 + 4];
            acc[0] = fmaf(x, w0.x, acc[0]); acc[1] = fmaf(x, w0.y, acc[1]);
            acc[2] = fmaf(x, w0.z, acc[2]); acc[3] = fmaf(x, w0.w, acc[3]);
            acc[4] = fmaf(x, w1.x, acc[4]); acc[5] = fmaf(x, w1.y, acc[5]);
            acc[6] = fmaf(x, w1.z, acc[6]); acc[7] = fmaf(x, w1.w, acc[7]);
        }
    }
    float pl = 0.f, pr = 0.f;
#pragma unroll
    for (int j = 0; j < 8; ++j) {
        pl = fmaf(acc[j], al8[j], pl);
        pr = fmaf(acc[j], ar8[j], pr);
    }
    pl += __shfl_xor(pl, 1, 64); pl += __shfl_xor(pl, 2, 64); pl += __shfl_xor(pl, 4, 64);
    pr += __shfl_xor(pr, 1, 64); pr += __shfl_xor(pr, 2, 64); pr += __shfl_xor(pr, 4, 64);
    if (cg == 0) {
        const float el = pl;
        // m_i = leaky(e_l + 8): row upper bound; softmax shift-invariance makes it EXACT.
        const float s8 = el + 8.0f;
        const float m = fmaxf(s8, 0.2f * s8);
        el2p[row] = (el - m) * LOG2E;
        cpv[row] = -0.8f * m * LOG2E;
        erp[row] = pr * LOG2E;
    }
#pragma unroll
    for (int j = 0; j < 8; ++j) HbT[(c0 + j) * NN + row] = f2b(acc[j]);
}

// ---------------- Kernel 2: counted-vmcnt pipeline; 256-thr blocks, 5 groups/CU -----
// grid 1024 x 256; block = 16 rows x 4096 cols (16 tiles of 256).
// R16 deltas: (a) plain-C RTZ bf16 pack in phase1 (no inline asm);
//             (b) __launch_bounds__(256,5) -> 5 blocks/CU.
__global__ __launch_bounds__(256, 5) void gat_main(
    const int* __restrict__ A, const unsigned short* __restrict__ HbT,
    const float* __restrict__ el2p, const float* __restrict__ cpv,
    const float* __restrict__ erp, float* __restrict__ out, float* __restrict__ dsum)
{
    __shared__ unsigned short plds[2][16 * 264]; // bf16 p, row stride 264
    const int t = threadIdx.x;
    const int l = t & 63;
    const int w = t >> 6;                        // 4 waves
    const int rowbase = (blockIdx.x >> 1) * 16;
    const int jq16 = (blockIdx.x & 1) * 16;      // first of 16 owned 256-col tiles
    const int l15 = l & 15, lq = l >> 4;

    float el2c[4], cpc[4];
    const int4* Ap[4];
#pragma unroll
    for (int i = 0; i < 4; ++i) {
        const int gr = rowbase + 4 * i + w;
        el2c[i] = el2p[gr];
        cpc[i] = cpv[gr];
        Ap[i] = (const int4*)(A + (long)gr * NN + 4 * l);
    }
    f32x4 acc = {0.f, 0.f, 0.f, 0.f};
    f32x4 accs = {0.f, 0.f, 0.f, 0.f};   // rowsum via ones-B MFMA (wave 0)
    union { unsigned short s[8]; short8v v; } ones;
#pragma unroll
    for (int i = 0; i < 8; ++i) ones.s[i] = 0x3F80; // bf16 1.0
    const bool do_sum = (w == 0);
    const unsigned short* bbase = HbT + (long)(w * 16 + l15) * NN + lq * 8;
    const int aoff = l15 * 264 + lq * 8;

    int4 A0[4], A1[4];
    float4 E0, E1;
    short8v Bf[8];

    auto loadT = [&](int4* av, float4& e4, int jt) {
        const int jb4 = jt * 64;
#pragma unroll
        for (int i = 0; i < 4; ++i) av[i] = Ap[i][jb4];
        e4 = *(const float4*)(erp + jt * 256 + 4 * l);
    };

    auto issueB = [&](int jt) {
        const unsigned short* bp = bbase + (long)jt * 256;
#pragma unroll
        for (int kc = 0; kc < 8; ++kc) Bf[kc] = *(const short8v*)(bp + kc * 32);
    };

    auto phase1 = [&](const int4* av, const float4 e4, unsigned short* buf) {
        const float e[4] = {e4.x, e4.y, e4.z, e4.w};
#pragma unroll
        for (int i = 0; i < 4; ++i) {
            const int am[4] = {av[i].x, av[i].y, av[i].z, av[i].w};
            float p[4];
#pragma unroll
            for (int c = 0; c < 4; ++c) {
                const float u = el2c[i] + e[c];
                const float v = fmaf(u, 0.2f, cpc[i]);
                float g = fmaxf(u, v);
                g = am[c] ? g : -1e30f; // non-edge -> exp2 -> 0
                p[c] = __builtin_amdgcn_exp2f(g);
            }
            // RTZ bf16 pack, plain C (numerator & denominator use SAME fragments,
            // so the truncation mostly cancels in the softmax ratio)
            const unsigned int lo = (__float_as_uint(p[0]) >> 16) |
                                    (__float_as_uint(p[1]) & 0xffff0000u);
            const unsigned int hi = (__float_as_uint(p[2]) >> 16) |
                                    (__float_as_uint(p[3]) & 0xffff0000u);
            *(uint2v*)(buf + (4 * i + w) * 264 + 4 * l) = (uint2v){lo, hi};
        }
    };

    auto mfmaT = [&](const unsigned short* buf) {
        __builtin_amdgcn_s_setprio(1);
#pragma unroll
        for (int kc = 0; kc < 8; ++kc) {
            short8v af = *(const short8v*)(buf + aoff + kc * 32);
            acc = __builtin_amdgcn_mfma_f32_16x16x32_bf16(af, Bf[kc], acc, 0, 0, 0);
            if (do_sum)
                accs = __builtin_amdgcn_mfma_f32_16x16x32_bf16(af, ones.v, accs, 0, 0, 0);
        }
        __builtin_amdgcn_s_setprio(0);
    };

    loadT(A0, E0, jq16);
    loadT(A1, E1, jq16 + 1);
#pragma unroll
    for (int s = 0; s < 8; ++s) {
        const int jt = jq16 + 2 * s;
        issueB(jt);                    // B issued FIRST: its wait leaves A-prefetch alive
        PIN();
        phase1(A0, E0, plds[0]);
        if (s < 7) loadT(A0, E0, jt + 2);
        BAR();                         // lgkmcnt(0) + s_barrier; vmcnt NOT drained
        mfmaT(plds[0]);
        issueB(jt + 1);
        PIN();
        phase1(A1, E1, plds[1]);
        if (s < 7) loadT(A1, E1, jt + 3);
        BAR();
        mfmaT(plds[1]);
    }

    // denominator partials: accs[r] = rowsum(lq*4+r), replicated over l15
    if (do_sum && l15 == 0)
#pragma unroll
        for (int r = 0; r < 4; ++r)
            atomicAdd(dsum + rowbase + lq * 4 + r, accs[r]);
    // numerator partials
#pragma unroll
    for (int r = 0; r < 4; ++r) {
        const int row = lq * 4 + r;   // D layout: col=lane&15, row=(lane>>4)*4+r
        atomicAdd(out + (long)(rowbase + row) * HDIM + w * 16 + l15, acc[r]);
    }
}

// ---------------- Kernel 3: out *= 1/dsum[row] ------------------------------------
__global__ __launch_bounds__(256) void gat_norm(float* __restrict__ out,
                                                const float* __restrict__ dsum)
{
    const int i4 = blockIdx.x * 256 + threadIdx.x; // float4 index; 16 per row
    float4 v = ((float4*)out)[i4];
    const float ri = 1.0f / dsum[i4 >> 4];
    v.x *= ri; v.y *= ri; v.z *= ri; v.w *= ri;
    ((float4*)out)[i4] = v;
}

extern "C" void kernel_launch(void* const* d_in, const int* in_sizes, int n_in,
                              void* d_out, int out_size, void* d_ws, size_t ws_size,
                              hipStream_t stream) {
    const float *X = nullptr, *W = nullptr, *al = nullptr, *ar = nullptr;
    const int* A = nullptr;
    for (int i = 0; i < n_in; ++i) {
        const long s = in_sizes[i];
        if (s == (long)NN * NN) A = (const int*)d_in[i];
        else if (s == (long)NN * KDIM) X = (const float*)d_in[i];
        else if (s == (long)KDIM * HDIM) W = (const float*)d_in[i];
        else if (s == HDIM) { if (!al) al = (const float*)d_in[i]; else ar = (const float*)d_in[i]; }
    }
    float* out = (float*)d_out;
    // ws: HbT (1MB) + el2p/cpv/erp/dsum (4 x 32KB)
    unsigned short* HbT = (unsigned short*)d_ws;
    float* el2p = (float*)((char*)d_ws + (long)NN * HDIM * 2);
    float* cpv = el2p + NN;
    float* erp = cpv + NN;
    float* dsum = erp + NN;
    hipLaunchKernelGGL(gat_prep, dim3(256), dim3(256), 0, stream, X, W, al, ar, HbT, el2p, cpv, erp, out, dsum);
    hipLaunchKernelGGL(gat_main, dim3(1024), dim3(256), 0, stream, A, HbT, el2p, cpv, erp, out, dsum);
    hipLaunchKernelGGL(gat_norm, dim3(512), dim3(256), 0, stream, out, dsum);
}

// Round 17
// 91.809 us; speedup vs baseline: 1.4087x; 1.4087x over previous
//
#include <hip/hip_runtime.h>

typedef __attribute__((ext_vector_type(8))) short short8v;
typedef __attribute__((ext_vector_type(4))) float f32x4;
typedef __attribute__((ext_vector_type(2))) unsigned int uint2v;

#define NN 8192
#define HDIM 64
#define KDIM 128
#define LOG2E 1.44269504088896340736f

#define PIN() asm volatile("" ::: "memory")
// Barrier WITHOUT vmcnt drain: LDS hazards need only lgkmcnt(0).
#define BAR() asm volatile("s_waitcnt lgkmcnt(0)\n\ts_barrier" ::: "memory")

__device__ __forceinline__ unsigned short f2b(float f) {
    unsigned int u = __float_as_uint(f);
    return (unsigned short)((u + 0x7fffu + ((u >> 16) & 1u)) >> 16);
}

// ---------------- Kernel 1 (R14/R15-verified): H = X@W, consts, HbT bf16, zero-fill ----
__global__ __launch_bounds__(256) void gat_prep(
    const float* __restrict__ X, const float* __restrict__ W,
    const float* __restrict__ al, const float* __restrict__ ar,
    unsigned short* __restrict__ HbT, float* __restrict__ el2p,
    float* __restrict__ cpv, float* __restrict__ erp,
    float* __restrict__ outz, float* __restrict__ dsumz)
{
    __shared__ float Wl[KDIM * HDIM];
    const int t = threadIdx.x;
    {   // zero-fill accumulation buffers (131072 float4 = 2MB out; 8192 dsum)
        const int gt = blockIdx.x * 256 + t;
        const float4 z = {0.f, 0.f, 0.f, 0.f};
        float4* ov = (float4*)outz;
        ov[gt] = z;
        ov[gt + 65536] = z;
        if (blockIdx.x < 32) dsumz[gt] = 0.f;
    }
    {
        const float4* Wv = (const float4*)W;
        float4* Wlv = (float4*)Wl;
#pragma unroll
        for (int s = 0; s < 8; ++s) Wlv[t + s * 256] = Wv[t + s * 256];
    }
    __syncthreads();
    const int row = blockIdx.x * 32 + (t >> 3);
    const int cg = t & 7;
    const int c0 = cg * 8;
    float al8[8], ar8[8];
#pragma unroll
    for (int j = 0; j < 8; ++j) { al8[j] = al[c0 + j]; ar8[j] = ar[c0 + j]; }
    float acc[8];
#pragma unroll
    for (int j = 0; j < 8; ++j) acc[j] = 0.f;
    const float4* Xv = (const float4*)(X + row * KDIM);
    for (int k4 = 0; k4 < 32; ++k4) {
        float4 x4 = Xv[k4];
        float xs[4] = {x4.x, x4.y, x4.z, x4.w};
#pragma unroll
        for (int kk = 0; kk < 4; ++kk) {
            const int k = k4 * 4 + kk;
            const float x = xs[kk];
            const float4 w0 = *(const float4*)&Wl[k * HDIM + c0];
            const float4 w1 = *(const float4*)&Wl[k * HDIM + c0 + 4];
            acc[0] = fmaf(x, w0.x, acc[0]); acc[1] = fmaf(x, w0.y, acc[1]);
            acc[2] = fmaf(x, w0.z, acc[2]); acc[3] = fmaf(x, w0.w, acc[3]);
            acc[4] = fmaf(x, w1.x, acc[4]); acc[5] = fmaf(x, w1.y, acc[5]);
            acc[6] = fmaf(x, w1.z, acc[6]); acc[7] = fmaf(x, w1.w, acc[7]);
        }
    }
    float pl = 0.f, pr = 0.f;
#pragma unroll
    for (int j = 0; j < 8; ++j) {
        pl = fmaf(acc[j], al8[j], pl);
        pr = fmaf(acc[j], ar8[j], pr);
    }
    pl += __shfl_xor(pl, 1, 64); pl += __shfl_xor(pl, 2, 64); pl += __shfl_xor(pl, 4, 64);
    pr += __shfl_xor(pr, 1, 64); pr += __shfl_xor(pr, 2, 64); pr += __shfl_xor(pr, 4, 64);
    if (cg == 0) {
        const float el = pl;
        // m_i = leaky(e_l + 8): row upper bound; softmax shift-invariance makes it EXACT.
        const float s8 = el + 8.0f;
        const float m = fmaxf(s8, 0.2f * s8);
        el2p[row] = (el - m) * LOG2E;
        cpv[row] = -0.8f * m * LOG2E;
        erp[row] = pr * LOG2E;
    }
#pragma unroll
    for (int j = 0; j < 8; ++j) HbT[(c0 + j) * NN + row] = f2b(acc[j]);
}

// ---------------- Kernel 2: counted-vmcnt pipeline; 256-thr blocks, 4 groups/CU -----
// grid 1024 x 256; block = 16 rows x 4096 cols (16 tiles of 256). 4 blocks/CU.
// R17 = R15 + RTZ pack ONLY (R16's launch_bounds(256,5) reverted: VGPR=48 spilled).
__global__ __launch_bounds__(256, 4) void gat_main(
    const int* __restrict__ A, const unsigned short* __restrict__ HbT,
    const float* __restrict__ el2p, const float* __restrict__ cpv,
    const float* __restrict__ erp, float* __restrict__ out, float* __restrict__ dsum)
{
    __shared__ unsigned short plds[2][16 * 264]; // bf16 p, row stride 264
    const int t = threadIdx.x;
    const int l = t & 63;
    const int w = t >> 6;                        // 4 waves
    const int rowbase = (blockIdx.x >> 1) * 16;
    const int jq16 = (blockIdx.x & 1) * 16;      // first of 16 owned 256-col tiles
    const int l15 = l & 15, lq = l >> 4;

    float el2c[4], cpc[4];
    const int4* Ap[4];
#pragma unroll
    for (int i = 0; i < 4; ++i) {
        const int gr = rowbase + 4 * i + w;
        el2c[i] = el2p[gr];
        cpc[i] = cpv[gr];
        Ap[i] = (const int4*)(A + (long)gr * NN + 4 * l);
    }
    f32x4 acc = {0.f, 0.f, 0.f, 0.f};
    f32x4 accs = {0.f, 0.f, 0.f, 0.f};   // rowsum via ones-B MFMA (wave 0)
    union { unsigned short s[8]; short8v v; } ones;
#pragma unroll
    for (int i = 0; i < 8; ++i) ones.s[i] = 0x3F80; // bf16 1.0
    const bool do_sum = (w == 0);
    const unsigned short* bbase = HbT + (long)(w * 16 + l15) * NN + lq * 8;
    const int aoff = l15 * 264 + lq * 8;

    int4 A0[4], A1[4];
    float4 E0, E1;
    short8v Bf[8];

    auto loadT = [&](int4* av, float4& e4, int jt) {
        const int jb4 = jt * 64;
#pragma unroll
        for (int i = 0; i < 4; ++i) av[i] = Ap[i][jb4];
        e4 = *(const float4*)(erp + jt * 256 + 4 * l);
    };

    auto issueB = [&](int jt) {
        const unsigned short* bp = bbase + (long)jt * 256;
#pragma unroll
        for (int kc = 0; kc < 8; ++kc) Bf[kc] = *(const short8v*)(bp + kc * 32);
    };

    auto phase1 = [&](const int4* av, const float4 e4, unsigned short* buf) {
        const float e[4] = {e4.x, e4.y, e4.z, e4.w};
#pragma unroll
        for (int i = 0; i < 4; ++i) {
            const int am[4] = {av[i].x, av[i].y, av[i].z, av[i].w};
            float p[4];
#pragma unroll
            for (int c = 0; c < 4; ++c) {
                const float u = el2c[i] + e[c];
                const float v = fmaf(u, 0.2f, cpc[i]);
                float g = fmaxf(u, v);
                g = am[c] ? g : -1e30f; // non-edge -> exp2 -> 0
                p[c] = __builtin_amdgcn_exp2f(g);
            }
            // RTZ bf16 pack, plain C (R16-verified: absmax unchanged — the
            // truncation cancels in the softmax ratio since numerator and
            // denominator consume the SAME fragments via the ones-MFMA).
            const unsigned int lo = (__float_as_uint(p[0]) >> 16) |
                                    (__float_as_uint(p[1]) & 0xffff0000u);
            const unsigned int hi = (__float_as_uint(p[2]) >> 16) |
                                    (__float_as_uint(p[3]) & 0xffff0000u);
            *(uint2v*)(buf + (4 * i + w) * 264 + 4 * l) = (uint2v){lo, hi};
        }
    };

    auto mfmaT = [&](const unsigned short* buf) {
        __builtin_amdgcn_s_setprio(1);
#pragma unroll
        for (int kc = 0; kc < 8; ++kc) {
            short8v af = *(const short8v*)(buf + aoff + kc * 32);
            acc = __builtin_amdgcn_mfma_f32_16x16x32_bf16(af, Bf[kc], acc, 0, 0, 0);
            if (do_sum)
                accs = __builtin_amdgcn_mfma_f32_16x16x32_bf16(af, ones.v, accs, 0, 0, 0);
        }
        __builtin_amdgcn_s_setprio(0);
    };

    loadT(A0, E0, jq16);
    loadT(A1, E1, jq16 + 1);
#pragma unroll
    for (int s = 0; s < 8; ++s) {
        const int jt = jq16 + 2 * s;
        issueB(jt);                    // B issued FIRST: its wait leaves A-prefetch alive
        PIN();
        phase1(A0, E0, plds[0]);
        if (s < 7) loadT(A0, E0, jt + 2);
        BAR();                         // lgkmcnt(0) + s_barrier; vmcnt NOT drained
        mfmaT(plds[0]);
        issueB(jt + 1);
        PIN();
        phase1(A1, E1, plds[1]);
        if (s < 7) loadT(A1, E1, jt + 3);
        BAR();
        mfmaT(plds[1]);
    }

    // denominator partials: accs[r] = rowsum(lq*4+r), replicated over l15
    if (do_sum && l15 == 0)
#pragma unroll
        for (int r = 0; r < 4; ++r)
            atomicAdd(dsum + rowbase + lq * 4 + r, accs[r]);
    // numerator partials
#pragma unroll
    for (int r = 0; r < 4; ++r) {
        const int row = lq * 4 + r;   // D layout: col=lane&15, row=(lane>>4)*4+r
        atomicAdd(out + (long)(rowbase + row) * HDIM + w * 16 + l15, acc[r]);
    }
}

// ---------------- Kernel 3: out *= 1/dsum[row] ------------------------------------
__global__ __launch_bounds__(256) void gat_norm(float* __restrict__ out,
                                                const float* __restrict__ dsum)
{
    const int i4 = blockIdx.x * 256 + threadIdx.x; // float4 index; 16 per row
    float4 v = ((float4*)out)[i4];
    const float ri = 1.0f / dsum[i4 >> 4];
    v.x *= ri; v.y *= ri; v.z *= ri; v.w *= ri;
    ((float4*)out)[i4] = v;
}

extern "C" void kernel_launch(void* const* d_in, const int* in_sizes, int n_in,
                              void* d_out, int out_size, void* d_ws, size_t ws_size,
                              hipStream_t stream) {
    const float *X = nullptr, *W = nullptr, *al = nullptr, *ar = nullptr;
    const int* A = nullptr;
    for (int i = 0; i < n_in; ++i) {
        const long s = in_sizes[i];
        if (s == (long)NN * NN) A = (const int*)d_in[i];
        else if (s == (long)NN * KDIM) X = (const float*)d_in[i];
        else if (s == (long)KDIM * HDIM) W = (const float*)d_in[i];
        else if (s == HDIM) { if (!al) al = (const float*)d_in[i]; else ar = (const float*)d_in[i]; }
    }
    float* out = (float*)d_out;
    // ws: HbT (1MB) + el2p/cpv/erp/dsum (4 x 32KB)
    unsigned short* HbT = (unsigned short*)d_ws;
    float* el2p = (float*)((char*)d_ws + (long)NN * HDIM * 2);
    float* cpv = el2p + NN;
    float* erp = cpv + NN;
    float* dsum = erp + NN;
    hipLaunchKernelGGL(gat_prep, dim3(256), dim3(256), 0, stream, X, W, al, ar, HbT, el2p, cpv, erp, out, dsum);
    hipLaunchKernelGGL(gat_main, dim3(1024), dim3(256), 0, stream, A, HbT, el2p, cpv, erp, out, dsum);
    hipLaunchKernelGGL(gat_norm, dim3(512), dim3(256), 0, stream, out, dsum);
}

// Round 19
// 89.653 us; speedup vs baseline: 1.4426x; 1.0240x over previous
//
#include <hip/hip_runtime.h>

typedef __attribute__((ext_vector_type(8))) short short8v;
typedef __attribute__((ext_vector_type(4))) float f32x4;
typedef __attribute__((ext_vector_type(2))) unsigned int uint2v;

#define NN 8192
#define HDIM 64
#define KDIM 128
#define LOG2E 1.44269504088896340736f

#if defined(__has_builtin)
#if __has_builtin(__builtin_amdgcn_cvt_pk_fp8_f32) && __has_builtin(__builtin_amdgcn_mfma_f32_16x16x32_fp8_fp8)
#define FP8PATH 1
#endif
#endif

#define PIN() asm volatile("" ::: "memory")
// Barrier WITHOUT vmcnt drain: LDS hazards need only lgkmcnt(0).
#define BAR() asm volatile("s_waitcnt lgkmcnt(0)\n\ts_barrier" ::: "memory")

__device__ __forceinline__ unsigned short f2b(float f) {
    unsigned int u = __float_as_uint(f);
    return (unsigned short)((u + 0x7fffu + ((u >> 16) & 1u)) >> 16);
}

// ---------------- Kernel 1: H = X@W, consts (fp8-scaled), HbT, fused zero-fill ------
__global__ __launch_bounds__(256) void gat_prep(
    const float* __restrict__ X, const float* __restrict__ W,
    const float* __restrict__ al, const float* __restrict__ ar,
    void* __restrict__ HbTv, float* __restrict__ el2p,
    float* __restrict__ cpv, float* __restrict__ erp,
    float* __restrict__ outz, float* __restrict__ dsumz)
{
    __shared__ float Wl[KDIM * HDIM];
    const int t = threadIdx.x;
    {   // zero-fill accumulation buffers (131072 float4 = 2MB out; 8192 dsum)
        const int gt = blockIdx.x * 256 + t;
        const float4 z = {0.f, 0.f, 0.f, 0.f};
        float4* ov = (float4*)outz;
        ov[gt] = z;
        ov[gt + 65536] = z;
        if (blockIdx.x < 32) dsumz[gt] = 0.f;
    }
    {
        const float4* Wv = (const float4*)W;
        float4* Wlv = (float4*)Wl;
#pragma unroll
        for (int s = 0; s < 8; ++s) Wlv[t + s * 256] = Wv[t + s * 256];
    }
    __syncthreads();
    const int row = blockIdx.x * 32 + (t >> 3);
    const int cg = t & 7;
    const int c0 = cg * 8;
    float al8[8], ar8[8];
#pragma unroll
    for (int j = 0; j < 8; ++j) { al8[j] = al[c0 + j]; ar8[j] = ar[c0 + j]; }
    float acc[8];
#pragma unroll
    for (int j = 0; j < 8; ++j) acc[j] = 0.f;
    const float4* Xv = (const float4*)(X + row * KDIM);
    for (int k4 = 0; k4 < 32; ++k4) {
        float4 x4 = Xv[k4];
        float xs[4] = {x4.x, x4.y, x4.z, x4.w};
#pragma unroll
        for (int kk = 0; kk < 4; ++kk) {
            const int k = k4 * 4 + kk;
            const float x = xs[kk];
            const float4 w0 = *(const float4*)&Wl[k * HDIM + c0];
            const float4 w1 = *(const float4*)&Wl[k * HDIM + c0 + 4];
            acc[0] = fmaf(x, w0.x, acc[0]); acc[1] = fmaf(x, w0.y, acc[1]);
            acc[2] = fmaf(x, w0.z, acc[2]); acc[3] = fmaf(x, w0.w, acc[3]);
            acc[4] = fmaf(x, w1.x, acc[4]); acc[5] = fmaf(x, w1.y, acc[5]);
            acc[6] = fmaf(x, w1.z, acc[6]); acc[7] = fmaf(x, w1.w, acc[7]);
        }
    }
    float pl = 0.f, pr = 0.f;
#pragma unroll
    for (int j = 0; j < 8; ++j) {
        pl = fmaf(acc[j], al8[j], pl);
        pr = fmaf(acc[j], ar8[j], pr);
    }
    pl += __shfl_xor(pl, 1, 64); pl += __shfl_xor(pl, 2, 64); pl += __shfl_xor(pl, 4, 64);
    pr += __shfl_xor(pr, 1, 64); pr += __shfl_xor(pr, 2, 64); pr += __shfl_xor(pr, 4, 64);
    if (cg == 0) {
        const float el = pl;
        // m_i = leaky(e_l + 8): row upper bound (EXACT via shift-invariance), PLUS a
        // +8 exponent rescale so p' = e^{leaky(el+er)-el} ~ 1 sits in fp8's range
        // (max ~74 << 448 sat; min ~0.011 >= denormal floor). Cancels in the ratio.
        const float s8 = el + 8.0f;
        const float m = fmaxf(s8, 0.2f * s8);
        el2p[row] = (el - m + 8.0f) * LOG2E;
        cpv[row] = (-0.8f * m + 6.4f) * LOG2E;   // leaky branch lands at (0.2(el+er)-m+8)L
        erp[row] = pr * LOG2E;
    }
#ifdef FP8PATH
    unsigned char* HbT8 = (unsigned char*)HbTv;
#pragma unroll
    for (int j = 0; j < 8; ++j) {
        const unsigned int b8 =
            (unsigned int)__builtin_amdgcn_cvt_pk_fp8_f32(acc[j], acc[j], 0, false) & 0xffu;
        HbT8[(long)(c0 + j) * NN + row] = (unsigned char)b8;
    }
#else
    unsigned short* HbT = (unsigned short*)HbTv;
#pragma unroll
    for (int j = 0; j < 8; ++j) HbT[(long)(c0 + j) * NN + row] = f2b(acc[j]);
#endif
}

// ---------------- Kernel 2: counted-vmcnt pipeline; fp8 B-path (halved L2 traffic) ---
// grid 1024 x 256; block = 16 rows x 4096 cols (16 tiles of 256). 4 blocks/CU.
__global__ __launch_bounds__(256, 4) void gat_main(
    const int* __restrict__ A, const void* __restrict__ HbTv,
    const float* __restrict__ el2p, const float* __restrict__ cpv,
    const float* __restrict__ erp, float* __restrict__ out, float* __restrict__ dsum)
{
    const int t = threadIdx.x;
    const int l = t & 63;
    const int w = t >> 6;                        // 4 waves
    const int rowbase = (blockIdx.x >> 1) * 16;
    const int jq16 = (blockIdx.x & 1) * 16;      // first of 16 owned 256-col tiles
    const int l15 = l & 15, lq = l >> 4;

    float el2c[4], cpc[4];
    const int4* Ap[4];
#pragma unroll
    for (int i = 0; i < 4; ++i) {
        const int gr = rowbase + 4 * i + w;
        el2c[i] = el2p[gr];
        cpc[i] = cpv[gr];
        Ap[i] = (const int4*)(A + (long)gr * NN + 4 * l);
    }
    f32x4 acc = {0.f, 0.f, 0.f, 0.f};
    f32x4 accs = {0.f, 0.f, 0.f, 0.f};   // rowsum via ones-B MFMA (wave 0)
    const bool do_sum = (w == 0);

    int4 A0[4], A1[4];
    float4 E0, E1;

    auto loadT = [&](int4* av, float4& e4, int jt) {
        const int jb4 = jt * 64;
#pragma unroll
        for (int i = 0; i < 4; ++i) av[i] = Ap[i][jb4];
        e4 = *(const float4*)(erp + jt * 256 + 4 * l);
    };

#ifdef FP8PATH
    __shared__ __align__(16) unsigned char plds[2][16 * 264]; // fp8 p, row stride 264B
    const unsigned char* bbase = (const unsigned char*)HbTv + (long)(w * 16 + l15) * NN + lq * 8;
    const int aoff = l15 * 264 + lq * 8;
    const long long ONES8 = 0x3838383838383838LL; // e4m3 1.0 x8
    unsigned long long Bf[8];

    auto issueB = [&](int jt) {
        const unsigned char* bp = bbase + (long)jt * 256;
#pragma unroll
        for (int kc = 0; kc < 8; ++kc)
            Bf[kc] = *(const unsigned long long*)(bp + kc * 32);
    };

    auto phase1 = [&](const int4* av, const float4 e4, unsigned char* buf) {
        const float e[4] = {e4.x, e4.y, e4.z, e4.w};
#pragma unroll
        for (int i = 0; i < 4; ++i) {
            const int am[4] = {av[i].x, av[i].y, av[i].z, av[i].w};
            float p[4];
#pragma unroll
            for (int c = 0; c < 4; ++c) {
                const float u = el2c[i] + e[c];
                const float v = fmaf(u, 0.2f, cpc[i]);
                float g = fmaxf(u, v);
                g = am[c] ? g : -1e30f; // non-edge -> exp2 -> 0 -> fp8 0x00
                p[c] = __builtin_amdgcn_exp2f(g);
            }
            // e4m3 pack via builtins. num/denom share these fragments (ones-MFMA)
            // so quantization largely cancels in the softmax ratio.
            unsigned int pk = (unsigned int)__builtin_amdgcn_cvt_pk_fp8_f32(p[0], p[1], 0, false);
            pk = (unsigned int)__builtin_amdgcn_cvt_pk_fp8_f32(p[2], p[3], (int)pk, true);
            *(unsigned int*)(buf + (4 * i + w) * 264 + 4 * l) = pk;
        }
    };

    auto mfmaT = [&](const unsigned char* buf) {
        __builtin_amdgcn_s_setprio(1);
#pragma unroll
        for (int kc = 0; kc < 8; ++kc) {
            const long long af = *(const long long*)(buf + aoff + kc * 32);
            acc = __builtin_amdgcn_mfma_f32_16x16x32_fp8_fp8(af, (long long)Bf[kc], acc, 0, 0, 0);
            if (do_sum)
                accs = __builtin_amdgcn_mfma_f32_16x16x32_fp8_fp8(af, ONES8, accs, 0, 0, 0);
        }
        __builtin_amdgcn_s_setprio(0);
    };
#else
    __shared__ unsigned short plds[2][16 * 264]; // bf16 p, row stride 264 elems
    union { unsigned short s[8]; short8v v; } ones;
#pragma unroll
    for (int i = 0; i < 8; ++i) ones.s[i] = 0x3F80; // bf16 1.0
    const unsigned short* bbase = (const unsigned short*)HbTv + (long)(w * 16 + l15) * NN + lq * 8;
    const int aoff = l15 * 264 + lq * 8;
    short8v Bf[8];

    auto issueB = [&](int jt) {
        const unsigned short* bp = bbase + (long)jt * 256;
#pragma unroll
        for (int kc = 0; kc < 8; ++kc) Bf[kc] = *(const short8v*)(bp + kc * 32);
    };

    auto phase1 = [&](const int4* av, const float4 e4, unsigned short* buf) {
        const float e[4] = {e4.x, e4.y, e4.z, e4.w};
#pragma unroll
        for (int i = 0; i < 4; ++i) {
            const int am[4] = {av[i].x, av[i].y, av[i].z, av[i].w};
            float p[4];
#pragma unroll
            for (int c = 0; c < 4; ++c) {
                const float u = el2c[i] + e[c];
                const float v = fmaf(u, 0.2f, cpc[i]);
                float g = fmaxf(u, v);
                g = am[c] ? g : -1e30f;
                p[c] = __builtin_amdgcn_exp2f(g);
            }
            const unsigned int lo = (__float_as_uint(p[0]) >> 16) |
                                    (__float_as_uint(p[1]) & 0xffff0000u);
            const unsigned int hi = (__float_as_uint(p[2]) >> 16) |
                                    (__float_as_uint(p[3]) & 0xffff0000u);
            *(uint2v*)(buf + (4 * i + w) * 264 + 4 * l) = (uint2v){lo, hi};
        }
    };

    auto mfmaT = [&](const unsigned short* buf) {
        __builtin_amdgcn_s_setprio(1);
#pragma unroll
        for (int kc = 0; kc < 8; ++kc) {
            short8v af = *(const short8v*)(buf + aoff + kc * 32);
            acc = __builtin_amdgcn_mfma_f32_16x16x32_bf16(af, Bf[kc], acc, 0, 0, 0);
            if (do_sum)
                accs = __builtin_amdgcn_mfma_f32_16x16x32_bf16(af, ones.v, accs, 0, 0, 0);
        }
        __builtin_amdgcn_s_setprio(0);
    };
#endif

    loadT(A0, E0, jq16);
    loadT(A1, E1, jq16 + 1);
#pragma unroll
    for (int s = 0; s < 8; ++s) {
        const int jt = jq16 + 2 * s;
        issueB(jt);                    // B issued FIRST: its wait leaves A-prefetch alive
        PIN();
        phase1(A0, E0, plds[0]);
        if (s < 7) loadT(A0, E0, jt + 2);
        BAR();                         // lgkmcnt(0) + s_barrier; vmcnt NOT drained
        mfmaT(plds[0]);
        issueB(jt + 1);
        PIN();
        phase1(A1, E1, plds[1]);
        if (s < 7) loadT(A1, E1, jt + 3);
        BAR();
        mfmaT(plds[1]);
    }

    // denominator partials: accs[r] = rowsum(lq*4+r), replicated over l15
    if (do_sum && l15 == 0)
#pragma unroll
        for (int r = 0; r < 4; ++r)
            atomicAdd(dsum + rowbase + lq * 4 + r, accs[r]);
    // numerator partials
#pragma unroll
    for (int r = 0; r < 4; ++r) {
        const int row = lq * 4 + r;   // D layout: col=lane&15, row=(lane>>4)*4+r
        atomicAdd(out + (long)(rowbase + row) * HDIM + w * 16 + l15, acc[r]);
    }
}

// ---------------- Kernel 3: out *= 1/dsum[row] ------------------------------------
__global__ __launch_bounds__(256) void gat_norm(float* __restrict__ out,
                                                const float* __restrict__ dsum)
{
    const int i4 = blockIdx.x * 256 + threadIdx.x; // float4 index; 16 per row
    float4 v = ((float4*)out)[i4];
    const float ri = 1.0f / dsum[i4 >> 4];
    v.x *= ri; v.y *= ri; v.z *= ri; v.w *= ri;
    ((float4*)out)[i4] = v;
}

extern "C" void kernel_launch(void* const* d_in, const int* in_sizes, int n_in,
                              void* d_out, int out_size, void* d_ws, size_t ws_size,
                              hipStream_t stream) {
    const float *X = nullptr, *W = nullptr, *al = nullptr, *ar = nullptr;
    const int* A = nullptr;
    for (int i = 0; i < n_in; ++i) {
        const long s = in_sizes[i];
        if (s == (long)NN * NN) A = (const int*)d_in[i];
        else if (s == (long)NN * KDIM) X = (const float*)d_in[i];
        else if (s == (long)KDIM * HDIM) W = (const float*)d_in[i];
        else if (s == HDIM) { if (!al) al = (const float*)d_in[i]; else ar = (const float*)d_in[i]; }
    }
    float* out = (float*)d_out;
    // ws: HbT region (1MB reserved; fp8 uses 512KB of it) + el2p/cpv/erp/dsum
    void* HbTv = d_ws;
    float* el2p = (float*)((char*)d_ws + (long)NN * HDIM * 2);
    float* cpv = el2p + NN;
    float* erp = cpv + NN;
    float* dsum = erp + NN;
    hipLaunchKernelGGL(gat_prep, dim3(256), dim3(256), 0, stream, X, W, al, ar, HbTv, el2p, cpv, erp, out, dsum);
    hipLaunchKernelGGL(gat_main, dim3(1024), dim3(256), 0, stream, A, HbTv, el2p, cpv, erp, out, dsum);
    hipLaunchKernelGGL(gat_norm, dim3(512), dim3(256), 0, stream, out, dsum);
}